// Round 1
// baseline (249.205 us; speedup 1.0000x reference)
//
#include <hip/hip_runtime.h>
#include <math.h>

#define BB 32
#define AA 5
#define CC 80
#define HH 52
#define WW 52
#define NBOX 50
#define HWSZ (HH*WW)          // 2704
#define CELLS (AA*HWSZ)       // 13520
#define NF 16                 // floats per box record in workspace/LDS

__constant__ float d_aw[AA] = {1.3221f, 3.19275f, 5.05587f, 9.47112f, 11.2364f};
__constant__ float d_ah[AA] = {1.73145f, 4.00944f, 8.09892f, 4.84053f, 10.0071f};

__device__ __forceinline__ float sigmoidf(float x) { return 1.f / (1.f + __expf(-x) * 0.f + expf(-x) - expf(-x) + expf(-x)); }

// (the above is silly; use a clean one)
__device__ __forceinline__ float sig(float x) { return 1.f / (1.f + expf(-x)); }

// Kernel 1: per ground-truth box, compute best anchor, target cell, regression
// targets, iou_gt vs the predicted box at that cell, and corner-format gt box.
__global__ void region_prep(const float* __restrict__ pred,
                            const float* __restrict__ target,
                            float* __restrict__ boxws) {
    int b = blockIdx.x;
    int j = threadIdx.x;
    if (j >= NBOX) return;
    const float* t = target + ((size_t)b * NBOX + j) * 5;
    float cls = t[0];
    float raw_x = t[1];
    float gx = t[1] * (float)WW;
    float gy = t[2] * (float)HH;
    float gw = t[3] * (float)WW;
    float gh = t[4] * (float)HH;
    float valid = (raw_x > 0.f) ? 1.f : 0.f;

    // best anchor by wh-IoU (first max wins, like jnp.argmax)
    int best = 0; float bestv = -1.f;
    for (int a = 0; a < AA; ++a) {
        float inter = fminf(gw, d_aw[a]) * fminf(gh, d_ah[a]);
        float uni = gw * gh + d_aw[a] * d_ah[a] - inter;
        float r = inter / uni;
        if (r > bestv) { bestv = r; best = a; }
    }
    int gi = (int)gx; gi = gi < 0 ? 0 : (gi > WW - 1 ? WW - 1 : gi);
    int gj = (int)gy; gj = gj < 0 ? 0 : (gj > HH - 1 ? HH - 1 : gj);
    float tx_t = gx - (float)gi;
    float ty_t = gy - (float)gj;
    float tw_t = logf(gw / d_aw[best]);
    float th_t = logf(gh / d_ah[best]);

    // predicted box at (b, best, gj, gi)
    size_t base = ((size_t)(b * AA + best) * (CC + 5)) * HWSZ + (size_t)gj * WW + gi;
    float p0 = pred[base];
    float p1 = pred[base + HWSZ];
    float p2 = pred[base + 2 * HWSZ];
    float p3 = pred[base + 3 * HWSZ];
    float px = sig(p0) + (float)gi;
    float py = sig(p1) + (float)gj;
    float pw = expf(p2) * d_aw[best];
    float ph = expf(p3) * d_ah[best];

    // center-format IoU(gt, pred_box_at)
    float ax1 = gx - gw * 0.5f, ax2 = gx + gw * 0.5f;
    float ay1 = gy - gh * 0.5f, ay2 = gy + gh * 0.5f;
    float bx1 = px - pw * 0.5f, bx2 = px + pw * 0.5f;
    float by1 = py - ph * 0.5f, by2 = py + ph * 0.5f;
    float iw = fmaxf(fminf(ax2, bx2) - fmaxf(ax1, bx1), 0.f);
    float ih = fmaxf(fminf(ay2, by2) - fmaxf(ay1, by1), 0.f);
    float inter = iw * ih;
    float iou_gt = inter / (gw * gh + pw * ph - inter);

    float* o = boxws + ((size_t)b * NBOX + j) * NF;
    o[0] = valid;
    o[1] = (float)best;
    o[2] = (float)gi;
    o[3] = (float)gj;
    o[4] = tx_t; o[5] = ty_t; o[6] = tw_t; o[7] = th_t;
    o[8] = iou_gt;
    o[9] = cls;
    o[10] = ax1; o[11] = ax2; o[12] = ay1; o[13] = ay2;
    o[14] = gw * gh;
    o[15] = 0.f;
}

// Kernel 2: one thread per (a,h,w) cell, one blockIdx.y per batch.
__global__ __launch_bounds__(256) void region_loss(const float* __restrict__ pred,
                                                   const float* __restrict__ boxws,
                                                   float* __restrict__ out) {
    __shared__ float sh[NBOX * NF];
    __shared__ float wsum[4];
    int b = blockIdx.y;
    int tid = threadIdx.x;
    for (int i = tid; i < NBOX * NF; i += 256)
        sh[i] = boxws[(size_t)b * NBOX * NF + i];
    __syncthreads();

    int c = blockIdx.x * 256 + tid;
    float lsum = 0.f;
    if (c < CELLS) {
        int a = c / HWSZ;
        int rem = c - a * HWSZ;
        int hh = rem / WW;
        int wwi = rem - hh * WW;
        size_t base = ((size_t)(b * AA + a) * (CC + 5)) * HWSZ + rem;
        float p0 = pred[base];
        float p1 = pred[base + HWSZ];
        float p2 = pred[base + 2 * HWSZ];
        float p3 = pred[base + 3 * HWSZ];
        float p4 = pred[base + 4 * HWSZ];
        float tx = sig(p0);
        float ty = sig(p1);
        float conf = sig(p4);
        float bx = tx + (float)wwi;
        float by = ty + (float)hh;
        float bw = expf(p2) * d_aw[a];
        float bh = expf(p3) * d_ah[a];
        float px1 = bx - bw * 0.5f, px2 = bx + bw * 0.5f;
        float py1 = by - bh * 0.5f, py2 = by + bh * 0.5f;
        float parea = bw * bh;

        float maxiou = 0.f;
        int win = -1;
        #pragma unroll 5
        for (int j = 0; j < NBOX; ++j) {
            const float* s = sh + j * NF;
            if (s[0] != 0.f) {
                float iw = fmaxf(fminf(px2, s[11]) - fmaxf(px1, s[10]), 0.f);
                float ih = fmaxf(fminf(py2, s[13]) - fmaxf(py1, s[12]), 0.f);
                float inter = iw * ih;
                float iou = inter / (parea + s[14] - inter);
                maxiou = fmaxf(maxiou, iou);
                if ((int)s[1] == a && (int)s[2] == wwi && (int)s[3] == hh) win = j;  // last match wins
            }
        }

        float dx, dy, dw, dh, lconf;
        if (win >= 0) {
            const float* s = sh + win * NF;
            dx = tx - s[4]; dy = ty - s[5]; dw = p2 - s[6]; dh = p3 - s[7];
            float d = conf - s[8];
            lconf = 2.5f * d * d;   // 0.5 * OBJECT_SCALE * (conf - iou_gt)^2
            // class cross-entropy at this cell (last-writer's class)
            int tcls = (int)s[9];
            tcls = tcls < 0 ? 0 : (tcls > CC - 1 ? CC - 1 : tcls);
            size_t cbase = base + 5 * (size_t)HWSZ;
            float m = -INFINITY, ssum = 0.f, vt = 0.f;
            for (int k = 0; k < CC; ++k) {
                float v = pred[cbase + (size_t)k * HWSZ];
                if (k == tcls) vt = v;
                if (v > m) { ssum = ssum * expf(m - v) + 1.f; m = v; }
                else       { ssum += expf(v - m); }
            }
            lsum += (m + logf(ssum)) - vt;
        } else {
            dx = tx - 0.5f; dy = ty - 0.5f; dw = p2; dh = p3;
            float cm = (maxiou > 0.6f) ? 0.f : 1.f;
            lconf = 0.5f * cm * conf * conf;
        }
        lsum += 0.5f * (dx * dx + dy * dy + dw * dw + dh * dh) + lconf;
    }

    // block reduction: wave shuffle then LDS across 4 waves
    for (int off = 32; off > 0; off >>= 1)
        lsum += __shfl_down(lsum, off, 64);
    int wave = tid >> 6;
    if ((tid & 63) == 0) wsum[wave] = lsum;
    __syncthreads();
    if (tid == 0) {
        float tot = wsum[0] + wsum[1] + wsum[2] + wsum[3];
        atomicAdd(out, tot);
    }
}

extern "C" void kernel_launch(void* const* d_in, const int* in_sizes, int n_in,
                              void* d_out, int out_size, void* d_ws, size_t ws_size,
                              hipStream_t stream) {
    const float* pred = (const float*)d_in[0];
    const float* target = (const float*)d_in[1];
    // d_in[2] = train_out, always 0 -> scalar output
    float* out = (float*)d_out;
    float* boxws = (float*)d_ws;   // needs BB*NBOX*NF*4 = 102400 bytes

    hipMemsetAsync(out, 0, sizeof(float) * out_size, stream);
    region_prep<<<dim3(BB), dim3(64), 0, stream>>>(pred, target, boxws);
    dim3 grid((CELLS + 255) / 256, BB);
    region_loss<<<grid, dim3(256), 0, stream>>>(pred, boxws, out);
}

// Round 2
// 249.079 us; speedup vs baseline: 1.0005x; 1.0005x over previous
//
#include <hip/hip_runtime.h>
#include <math.h>

#define BB 32
#define AA 5
#define CC 80
#define HH 52
#define WW 52
#define NBOX 50
#define HWSZ (HH*WW)          // 2704
#define CELLS (AA*HWSZ)       // 13520

__constant__ float d_aw[AA] = {1.3221f, 3.19275f, 5.05587f, 9.47112f, 11.2364f};
__constant__ float d_ah[AA] = {1.73145f, 4.00944f, 8.09892f, 4.84053f, 10.0071f};

__device__ __forceinline__ float sig(float x) { return 1.f / (1.f + expf(-x)); }

// Box record: 4 x float4 per box.
//  r0: ax1, ax2, ay1, ay2        (corner-format gt box; zeros if invalid)
//  r1: area, best_a, gi, gj      (area=0, best_a=-1 if invalid -> never matches, iou 0)
//  r2: tx_t, ty_t, tw_t, th_t
//  r3: iou_gt, cls, valid, is_last

__device__ __forceinline__ void cell_of(const float* t, int& best, int& gi, int& gj, float& valid) {
    float gx = t[1] * (float)WW;
    float gy = t[2] * (float)HH;
    float gw = t[3] * (float)WW;
    float gh = t[4] * (float)HH;
    valid = (t[1] > 0.f) ? 1.f : 0.f;
    best = 0; float bestv = -1.f;
    #pragma unroll
    for (int a = 0; a < AA; ++a) {
        float inter = fminf(gw, d_aw[a]) * fminf(gh, d_ah[a]);
        float uni = gw * gh + d_aw[a] * d_ah[a] - inter;
        float r = inter / uni;
        if (r > bestv) { bestv = r; best = a; }
    }
    gi = (int)gx; gi = gi < 0 ? 0 : (gi > WW - 1 ? WW - 1 : gi);
    gj = (int)gy; gj = gj < 0 ? 0 : (gj > HH - 1 ? HH - 1 : gj);
}

__global__ void region_prep(const float* __restrict__ pred,
                            const float* __restrict__ target,
                            float4* __restrict__ boxws) {
    int b = blockIdx.x;
    int j = threadIdx.x;
    if (j >= NBOX) return;
    const float* t = target + ((size_t)b * NBOX + j) * 5;
    float gx = t[1] * (float)WW;
    float gy = t[2] * (float)HH;
    float gw = t[3] * (float)WW;
    float gh = t[4] * (float)HH;
    int best, gi, gj; float valid;
    cell_of(t, best, gi, gj, valid);

    float tx_t = gx - (float)gi;
    float ty_t = gy - (float)gj;
    float tw_t = logf(gw / d_aw[best]);
    float th_t = logf(gh / d_ah[best]);

    // predicted box at (b, best, gj, gi)
    size_t base = ((size_t)(b * AA + best) * (CC + 5)) * HWSZ + (size_t)gj * WW + gi;
    float px = sig(pred[base]) + (float)gi;
    float py = sig(pred[base + HWSZ]) + (float)gj;
    float pw = expf(pred[base + 2 * HWSZ]) * d_aw[best];
    float ph = expf(pred[base + 3 * HWSZ]) * d_ah[best];

    float ax1 = gx - gw * 0.5f, ax2 = gx + gw * 0.5f;
    float ay1 = gy - gh * 0.5f, ay2 = gy + gh * 0.5f;
    float bx1 = px - pw * 0.5f, bx2 = px + pw * 0.5f;
    float by1 = py - ph * 0.5f, by2 = py + ph * 0.5f;
    float iw = fmaxf(fminf(ax2, bx2) - fmaxf(ax1, bx1), 0.f);
    float ih = fmaxf(fminf(ay2, by2) - fmaxf(ay1, by1), 0.f);
    float inter = iw * ih;
    float iou_gt = inter / (gw * gh + pw * ph - inter);

    // last-writer flag: any later valid box mapping to the same (best,gi,gj)?
    float is_last = 1.f;
    for (int j2 = j + 1; j2 < NBOX; ++j2) {
        const float* t2 = target + ((size_t)b * NBOX + j2) * 5;
        int b2, i2, jj2; float v2;
        cell_of(t2, b2, i2, jj2, v2);
        if (v2 != 0.f && b2 == best && i2 == gi && jj2 == gj) is_last = 0.f;
    }

    float4* o = boxws + ((size_t)b * NBOX + j) * 4;
    if (valid != 0.f) {
        o[0] = make_float4(ax1, ax2, ay1, ay2);
        o[1] = make_float4(gw * gh, (float)best, (float)gi, (float)gj);
    } else {
        o[0] = make_float4(0.f, 0.f, 0.f, 0.f);
        o[1] = make_float4(0.f, -1.f, -1.f, -1.f);
    }
    o[2] = make_float4(tx_t, ty_t, tw_t, th_t);
    o[3] = make_float4(iou_gt, t[0], valid, is_last);
}

__device__ __forceinline__ float wave_max(float v) {
    #pragma unroll
    for (int off = 32; off > 0; off >>= 1) v = fmaxf(v, __shfl_xor(v, off, 64));
    return v;
}
__device__ __forceinline__ float wave_sum(float v) {
    #pragma unroll
    for (int off = 32; off > 0; off >>= 1) v += __shfl_xor(v, off, 64);
    return v;
}

// Class cross-entropy: one wave per (batch, winning box). 80 logits across lanes.
__global__ __launch_bounds__(256) void region_ce(const float* __restrict__ pred,
                                                 const float4* __restrict__ boxws,
                                                 float* __restrict__ out) {
    int b = blockIdx.x;
    int wave = threadIdx.x >> 6;
    int lane = threadIdx.x & 63;
    float acc = 0.f;
    for (int j = wave; j < NBOX; j += 4) {
        const float4* r = boxws + ((size_t)b * NBOX + j) * 4;
        float4 r1 = r[1];
        float4 r3 = r[3];
        if (r3.z == 0.f || r3.w == 0.f) continue;   // not valid or not last writer
        int a = (int)r1.y, gi = (int)r1.z, gj = (int)r1.w;
        size_t cbase = ((size_t)(b * AA + a) * (CC + 5) + 5) * HWSZ + (size_t)gj * WW + gi;
        float v1 = pred[cbase + (size_t)lane * HWSZ];
        float v2 = (lane < CC - 64) ? pred[cbase + (size_t)(lane + 64) * HWSZ] : -INFINITY;
        float mx = wave_max(fmaxf(v1, v2));
        float s = expf(v1 - mx) + ((lane < CC - 64) ? expf(v2 - mx) : 0.f);
        s = wave_sum(s);
        int tcls = (int)r3.y;
        tcls = tcls < 0 ? 0 : (tcls > CC - 1 ? CC - 1 : tcls);
        float vt = ((lane == tcls) ? v1 : 0.f) + ((lane + 64 == tcls) ? v2 : 0.f);
        vt = wave_sum(vt);
        if (lane == 0) acc += (mx + logf(s)) - vt;
    }
    if (lane == 0 && acc != 0.f) atomicAdd(out, acc);
}

// Main kernel: one thread per (a,h,w) cell, blockIdx.y = batch. Branchless box loop.
__global__ __launch_bounds__(256) void region_loss(const float* __restrict__ pred,
                                                   const float4* __restrict__ boxws,
                                                   float* __restrict__ out) {
    __shared__ float4 sh[NBOX * 4];
    __shared__ float wsum[4];
    int b = blockIdx.y;
    int tid = threadIdx.x;
    if (tid < NBOX * 4) sh[tid] = boxws[(size_t)b * NBOX * 4 + tid];
    __syncthreads();

    int c = blockIdx.x * 256 + tid;
    float lsum = 0.f;
    if (c < CELLS) {
        int a = c / HWSZ;
        int rem = c - a * HWSZ;
        int hh = rem / WW;
        int wwi = rem - hh * WW;
        size_t base = ((size_t)(b * AA + a) * (CC + 5)) * HWSZ + rem;
        float p0 = pred[base];
        float p1 = pred[base + HWSZ];
        float p2 = pred[base + 2 * HWSZ];
        float p3 = pred[base + 3 * HWSZ];
        float p4 = pred[base + 4 * HWSZ];
        float tx = sig(p0);
        float ty = sig(p1);
        float conf = sig(p4);
        float bx = tx + (float)wwi;
        float by = ty + (float)hh;
        float bw = expf(p2) * d_aw[a];
        float bh = expf(p3) * d_ah[a];
        float px1 = bx - bw * 0.5f, px2 = bx + bw * 0.5f;
        float py1 = by - bh * 0.5f, py2 = by + bh * 0.5f;
        float parea = bw * bh;
        float af = (float)a, wf = (float)wwi, hf = (float)hh;

        float maxiou = 0.f;
        int win = -1;
        #pragma unroll 2
        for (int j = 0; j < NBOX; ++j) {
            float4 r0 = sh[j * 4 + 0];
            float4 r1 = sh[j * 4 + 1];
            float iw = fmaxf(fminf(px2, r0.y) - fmaxf(px1, r0.x), 0.f);
            float ih = fmaxf(fminf(py2, r0.w) - fmaxf(py1, r0.z), 0.f);
            float inter = iw * ih;
            float iou = inter / (parea + r1.x - inter);
            maxiou = fmaxf(maxiou, iou);
            bool m = (r1.y == af) & (r1.z == wf) & (r1.w == hf);
            win = m ? j : win;
        }

        float dx, dy, dw, dh, lconf;
        if (win >= 0) {
            float4 r2 = sh[win * 4 + 2];
            float4 r3 = sh[win * 4 + 3];
            dx = tx - r2.x; dy = ty - r2.y; dw = p2 - r2.z; dh = p3 - r2.w;
            float d = conf - r3.x;
            lconf = 2.5f * d * d;           // 0.5 * OBJECT_SCALE * (conf - iou_gt)^2
        } else {
            dx = tx - 0.5f; dy = ty - 0.5f; dw = p2; dh = p3;
            float cm = (maxiou > 0.6f) ? 0.f : 1.f;
            lconf = 0.5f * cm * conf * conf;
        }
        lsum = 0.5f * (dx * dx + dy * dy + dw * dw + dh * dh) + lconf;
    }

    #pragma unroll
    for (int off = 32; off > 0; off >>= 1)
        lsum += __shfl_down(lsum, off, 64);
    int wave = tid >> 6;
    if ((tid & 63) == 0) wsum[wave] = lsum;
    __syncthreads();
    if (tid == 0) {
        atomicAdd(out, wsum[0] + wsum[1] + wsum[2] + wsum[3]);
    }
}

extern "C" void kernel_launch(void* const* d_in, const int* in_sizes, int n_in,
                              void* d_out, int out_size, void* d_ws, size_t ws_size,
                              hipStream_t stream) {
    const float* pred = (const float*)d_in[0];
    const float* target = (const float*)d_in[1];
    float* out = (float*)d_out;
    float4* boxws = (float4*)d_ws;   // BB*NBOX*4*16 = 102400 bytes

    hipMemsetAsync(out, 0, sizeof(float) * out_size, stream);
    region_prep<<<dim3(BB), dim3(64), 0, stream>>>(pred, target, boxws);
    region_ce<<<dim3(BB), dim3(256), 0, stream>>>(pred, boxws, out);
    dim3 grid((CELLS + 255) / 256, BB);
    region_loss<<<grid, dim3(256), 0, stream>>>(pred, boxws, out);
}